// Round 1
// baseline (289.411 us; speedup 1.0000x reference)
//
#include <hip/hip_runtime.h>
#include <math.h>

// SkipGRU: only chain j=23 contributes to the output (outputs[:, -1, :] with
// t=191 = chunk 7, lane 23; lanes are independent). So: 8 sequential GRU steps
// over x[:, c*24+23, :] with state h[256,512].
//
// Phase 1: MX[c][b][3U] = x[b, c*24+23, :] @ kernel + input_bias  (one GEMM, M=2048)
// Phase 2: for c in 0..7:  MI = h @ recurrent_kernel + recurrent_bias ; GRU update.

#define BB 256      // batch
#define UU 512      // units
#define NN 1536     // 3*U
#define KK 512      // F == U

// C[M][N] = gather(A)[M][K] @ W[K][N] + bias[N]
// Row m of A is at element offset: (m & 255)*rs + (m >> 8)*cs + co
// (covers both the x-select GEMM and the plain h GEMM).
__global__ __launch_bounds__(256)
void gemm_bias(const float* __restrict__ Abase, const float* __restrict__ W,
               const float* __restrict__ bias, float* __restrict__ C,
               int N, int K, int rs, int cs, int co)
{
    const int tid = threadIdx.x;
    const int tx = tid & 15;        // 16 cols of threads
    const int ty = tid >> 4;        // 16 rows of threads
    const int n0 = blockIdx.x * 64; // N tile
    const int m0 = blockIdx.y * 64; // M tile

    __shared__ float As[16][64];    // [k][m]
    __shared__ float Bs[16][64];    // [k][n]

    float acc[4][4] = {};

    // A tile loader: each thread loads one float4. 64 rows x 16 k.
    const int arow = tid >> 2;            // 0..63
    const int acol = (tid & 3) * 4;       // 0,4,8,12
    const int m = m0 + arow;
    const long aoff = (long)(m & 255) * rs + (long)(m >> 8) * cs + co;

    // B tile loader: each thread loads one float4. 16 k-rows x 64 cols.
    const int brow = tid >> 4;            // 0..15
    const int bcol = (tid & 15) * 4;      // 0..60

    for (int k0 = 0; k0 < K; k0 += 16) {
        float4 av = *(const float4*)(Abase + aoff + k0 + acol);
        As[acol + 0][arow] = av.x;
        As[acol + 1][arow] = av.y;
        As[acol + 2][arow] = av.z;
        As[acol + 3][arow] = av.w;
        float4 bv = *(const float4*)(W + (long)(k0 + brow) * N + n0 + bcol);
        *(float4*)&Bs[brow][bcol] = bv;
        __syncthreads();
        #pragma unroll
        for (int k = 0; k < 16; ++k) {
            float a[4], b[4];
            *(float4*)a = *(const float4*)&As[k][ty * 4];
            *(float4*)b = *(const float4*)&Bs[k][tx * 4];
            #pragma unroll
            for (int i = 0; i < 4; ++i)
                #pragma unroll
                for (int j = 0; j < 4; ++j)
                    acc[i][j] = fmaf(a[i], b[j], acc[i][j]);
        }
        __syncthreads();
    }

    const float4 bb = *(const float4*)(bias + n0 + tx * 4);
    #pragma unroll
    for (int i = 0; i < 4; ++i) {
        const int mm = m0 + ty * 4 + i;
        float4 r;
        r.x = acc[i][0] + bb.x;
        r.y = acc[i][1] + bb.y;
        r.z = acc[i][2] + bb.z;
        r.w = acc[i][3] + bb.w;
        *(float4*)(C + (long)mm * N + n0 + tx * 4) = r;
    }
}

// GRU elementwise update: hn = z*h + (1-z)*relu(xh + r*rh)
__global__ __launch_bounds__(256)
void gru_elem(const float* __restrict__ MXc, const float* __restrict__ MI,
              const float* __restrict__ h, float* __restrict__ hn)
{
    const int idx = blockIdx.x * 256 + threadIdx.x;   // b*512 + u
    const int b = idx >> 9;
    const int u = idx & 511;
    const float* mx = MXc + (long)b * NN;
    const float* mi = MI + (long)b * NN;
    const float xz = mx[u], xr = mx[u + UU], xh = mx[u + 2 * UU];
    const float rz = mi[u], rr = mi[u + UU], rh = mi[u + 2 * UU];
    const float z = 1.0f / (1.0f + __expf(-(xz + rz)));
    const float r = 1.0f / (1.0f + __expf(-(xr + rr)));
    const float cand = xh + r * rh;
    const float hh = cand > 0.0f ? cand : 0.0f;
    hn[idx] = z * h[idx] + (1.0f - z) * hh;
}

extern "C" void kernel_launch(void* const* d_in, const int* in_sizes, int n_in,
                              void* d_out, int out_size, void* d_ws, size_t ws_size,
                              hipStream_t stream)
{
    const float* x     = (const float*)d_in[0];   // [256,192,512]
    const float* ker   = (const float*)d_in[1];   // [512,1536]
    const float* rker  = (const float*)d_in[2];   // [512,1536]
    const float* ibias = (const float*)d_in[3];   // [1536]
    const float* rbias = (const float*)d_in[4];   // [1536]
    float* out = (float*)d_out;                   // [256,512]

    float* ws = (float*)d_ws;
    float* MX = ws;                                // 8*256*1536 = 3,145,728 f
    float* MI = MX + 8L * BB * NN;                 // 256*1536
    float* h0 = MI + (long)BB * NN;                // 256*512
    float* h1 = h0 + (long)BB * UU;                // 256*512

    hipMemsetAsync(h0, 0, (size_t)BB * UU * sizeof(float), stream);

    // Phase 1: MX = Xsel @ kernel + input_bias.  M=2048 (c*256+b), N=1536, K=512.
    // row offset = b*192*512 + (c*24+23)*512
    gemm_bias<<<dim3(NN / 64, 2048 / 64), 256, 0, stream>>>(
        x, ker, ibias, MX, NN, KK, 192 * 512, 24 * 512, 23 * 512);

    // Phase 2: sequential steps.
    float* hbuf[2] = { h0, h1 };
    for (int c = 0; c < 8; ++c) {
        float* hin  = hbuf[c & 1];
        float* hout = (c == 7) ? out : hbuf[(c + 1) & 1];
        gemm_bias<<<dim3(NN / 64, BB / 64), 256, 0, stream>>>(
            hin, rker, rbias, MI, NN, KK, UU, 0, 0);
        gru_elem<<<dim3(BB * UU / 256), 256, 0, stream>>>(
            MX + (long)c * BB * NN, MI, hin, hout);
    }
}

// Round 4
// 124.712 us; speedup vs baseline: 2.3206x; 2.3206x over previous
//
#include <hip/hip_runtime.h>
#include <hip/hip_bf16.h>
#include <math.h>

// SkipGRU on MI355X, round 2 design (3rd submit; two broker infra flakes):
// bf16 MFMA for both GEMM families + fused GRU epilogue in the step kernel.
//
// Only chain j=23 contributes to outputs[:, -1, :]  (t=191 = chunk 7 lane 23,
// lanes independent): 8 sequential GRU steps over x[:, c*24+23, :], h[256,512].
//
// Phase 0: transpose-convert weights to bf16 W^T[N][K]; gather+convert x rows.
// Phase 1: MX[c*256+b][3U] = Xsel @ kernel + input_bias   (bf16 MFMA, fp32 out)
// Phase 2: per chunk c: fused  (h @ R + rbias) -> GRU -> h  in one kernel.
//
// mfma_f32_16x16x32_bf16 layouts (learn_hip m89-verified):
//   A: lane l holds A[l&15][(l>>4)*8 + j]  (8 contiguous k -> bf16x8 load)
//   B: lane l holds B[(l>>4)*8 + j][l&15]  (B^T row-major -> contiguous load)
//   D: lane l reg q -> row (l>>4)*4+q, col l&15

typedef float f32x4 __attribute__((ext_vector_type(4)));
typedef short short8 __attribute__((ext_vector_type(8)));

#define BB 256
#define UU 512
#define KK 512
#define N3 1536

__device__ __forceinline__ float sigmoidf_(float s) {
    return 1.0f / (1.0f + __expf(-s));
}

// W[R][C] f32  ->  Wt[C][R] bf16   (LDS-tiled transpose)
__global__ __launch_bounds__(256)
void transpose_bf16(const float* __restrict__ W, __hip_bfloat16* __restrict__ Wt,
                    int R, int C)
{
    __shared__ float tile[32][33];
    const int x = threadIdx.x;          // 0..31
    const int y = threadIdx.y;          // 0..7
    const int c0 = blockIdx.x * 32;
    const int r0 = blockIdx.y * 32;
    #pragma unroll
    for (int i = 0; i < 32; i += 8)
        tile[y + i][x] = W[(long)(r0 + y + i) * C + c0 + x];
    __syncthreads();
    #pragma unroll
    for (int i = 0; i < 32; i += 8)
        Wt[(long)(c0 + y + i) * R + r0 + x] = __float2bfloat16(tile[x][y + i]);
}

// Gather the 8 needed timesteps of x and convert to bf16: Xb[c*256+b][k]
__global__ __launch_bounds__(256)
void convert_x(const float* __restrict__ x, __hip_bfloat16* __restrict__ Xb)
{
    const int idx = blockIdx.x * 256 + threadIdx.x;   // one thread per 8 elems
    const int e = idx * 8;
    const int m = e >> 9;              // 0..2047 = c*256+b
    const int kk = e & 511;
    const int b = m & 255, c = m >> 8;
    const float* src = x + (long)b * (192 * 512) + (long)(c * 24 + 23) * 512 + kk;
    float4 v0 = *(const float4*)src;
    float4 v1 = *(const float4*)(src + 4);
    __hip_bfloat16* dst = Xb + (long)m * 512 + kk;
    dst[0] = __float2bfloat16(v0.x);
    dst[1] = __float2bfloat16(v0.y);
    dst[2] = __float2bfloat16(v0.z);
    dst[3] = __float2bfloat16(v0.w);
    dst[4] = __float2bfloat16(v1.x);
    dst[5] = __float2bfloat16(v1.y);
    dst[6] = __float2bfloat16(v1.z);
    dst[7] = __float2bfloat16(v1.w);
}

// MX = A @ B^T^T + bias:  A[2048][512] bf16, Bt[1536][512] bf16 (=W^T), out f32.
// WG = 4 waves; wave = 16 rows x 64 cols (4 frags). Grid (1536/64, 2048/64).
__global__ __launch_bounds__(256)
void gemm_mx(const __hip_bfloat16* __restrict__ A,
             const __hip_bfloat16* __restrict__ Bt,
             const float* __restrict__ bias,
             float* __restrict__ C)
{
    const int tid = threadIdx.x;
    const int lane = tid & 63;
    const int wid = tid >> 6;                    // 0..3
    const int m0 = blockIdx.y * 64 + wid * 16;
    const int n0 = blockIdx.x * 64;
    const int lr = lane & 15;
    const int lk = (lane >> 4) * 8;

    const short8* ap = (const short8*)(A + (long)(m0 + lr) * KK + lk);
    const short8* bp = (const short8*)(Bt + (long)(n0 + lr) * KK + lk);

    f32x4 acc[4] = {{0.f,0.f,0.f,0.f},{0.f,0.f,0.f,0.f},
                    {0.f,0.f,0.f,0.f},{0.f,0.f,0.f,0.f}};
    #pragma unroll
    for (int k = 0; k < 16; ++k) {               // k0 = 32*k
        short8 a = ap[k * 4];
        #pragma unroll
        for (int t = 0; t < 4; ++t) {
            short8 b = bp[t * 1024 + k * 4];     // +16 rows = 16*512/8 short8
            acc[t] = __builtin_amdgcn_mfma_f32_16x16x32_bf16(a, b, acc[t], 0, 0, 0);
        }
    }
    const int row = (lane >> 4) * 4;
    #pragma unroll
    for (int t = 0; t < 4; ++t) {
        const int u = n0 + t * 16 + lr;
        const float bi = bias[u];
        #pragma unroll
        for (int q = 0; q < 4; ++q)
            C[(long)(m0 + row + q) * N3 + u] = acc[t][q] + bi;
    }
}

// One fused GRU step: MI = h @ R + rbias (3 gates), then elementwise update.
// Each wave owns one 16x16 (m,u) tile across ALL 3 gates -> lane-local fusion.
// Grid (512/32, 256/32), WG = 4 waves (2x2 tiles of 16x16).
__global__ __launch_bounds__(256)
void gru_step(const __hip_bfloat16* __restrict__ hbf,  // [256][512] bf16
              const float* __restrict__ hf,            // [256][512] f32
              const __hip_bfloat16* __restrict__ Rt,   // [1536][512] bf16 (R^T)
              const float* __restrict__ rbias,         // [1536]
              const float* __restrict__ MXc,           // [256][1536] f32
              float* __restrict__ hf_out,              // [256][512] f32
              __hip_bfloat16* __restrict__ hbf_out)    // [256][512] bf16
{
    const int tid = threadIdx.x;
    const int lane = tid & 63;
    const int wid = tid >> 6;
    const int wy = wid >> 1, wx = wid & 1;
    const int m0 = blockIdx.y * 32 + wy * 16;
    const int n0 = blockIdx.x * 32 + wx * 16;
    const int lr = lane & 15;
    const int lk = (lane >> 4) * 8;

    const short8* ap = (const short8*)(hbf + (long)(m0 + lr) * KK + lk);
    const short8* bp = (const short8*)(Rt + (long)(n0 + lr) * KK + lk);
    // gate g is +g*512 rows of Rt = g*512*512/8 = g*32768 short8

    f32x4 az = {0.f,0.f,0.f,0.f}, ar = {0.f,0.f,0.f,0.f}, ah = {0.f,0.f,0.f,0.f};
    #pragma unroll
    for (int k = 0; k < 16; ++k) {
        short8 a  = ap[k * 4];
        short8 bz = bp[k * 4];
        short8 br = bp[32768 + k * 4];
        short8 bh = bp[65536 + k * 4];
        az = __builtin_amdgcn_mfma_f32_16x16x32_bf16(a, bz, az, 0, 0, 0);
        ar = __builtin_amdgcn_mfma_f32_16x16x32_bf16(a, br, ar, 0, 0, 0);
        ah = __builtin_amdgcn_mfma_f32_16x16x32_bf16(a, bh, ah, 0, 0, 0);
    }

    const int row = (lane >> 4) * 4;
    const int u = n0 + lr;
    const float rbz = rbias[u];
    const float rbr = rbias[u + UU];
    const float rbh = rbias[u + 2 * UU];
    #pragma unroll
    for (int q = 0; q < 4; ++q) {
        const int m = m0 + row + q;
        const float* mx = MXc + (long)m * N3 + u;
        const float z = sigmoidf_(mx[0]      + az[q] + rbz);
        const float r = sigmoidf_(mx[UU]     + ar[q] + rbr);
        const float rh = ah[q] + rbh;
        const float cand = mx[2 * UU] + r * rh;      // xh + r*rh  (reset_after)
        const float hh = fmaxf(cand, 0.0f);          // relu
        const float hold = hf[(long)m * UU + u];
        const float hn = z * hold + (1.0f - z) * hh;
        hf_out[(long)m * UU + u] = hn;
        hbf_out[(long)m * UU + u] = __float2bfloat16(hn);
    }
}

extern "C" void kernel_launch(void* const* d_in, const int* in_sizes, int n_in,
                              void* d_out, int out_size, void* d_ws, size_t ws_size,
                              hipStream_t stream)
{
    const float* x     = (const float*)d_in[0];   // [256,192,512]
    const float* ker   = (const float*)d_in[1];   // [512,1536]
    const float* rker  = (const float*)d_in[2];   // [512,1536]
    const float* ibias = (const float*)d_in[3];   // [1536]
    const float* rbias = (const float*)d_in[4];   // [1536]
    float* out = (float*)d_out;                   // [256,512]

    char* ws = (char*)d_ws;
    float*          MX   = (float*)ws;                            // 12,582,912 B
    __hip_bfloat16* Xb   = (__hip_bfloat16*)(ws + 12582912);      //  2,097,152 B
    __hip_bfloat16* Kt   = (__hip_bfloat16*)(ws + 14680064);      //  1,572,864 B
    __hip_bfloat16* Rt   = (__hip_bfloat16*)(ws + 16252928);      //  1,572,864 B
    float*          hf0  = (float*)(ws + 17825792);               //    524,288 B
    __hip_bfloat16* hbf0 = (__hip_bfloat16*)(ws + 18350080);      //    262,144 B
    float*          hf1  = (float*)(ws + 18612224);               //    524,288 B
    __hip_bfloat16* hbf1 = (__hip_bfloat16*)(ws + 19136512);      //    262,144 B

    // Phase 0: weight transposes + x gather/convert + h=0 init
    transpose_bf16<<<dim3(48, 16), dim3(32, 8), 0, stream>>>(ker,  Kt, 512, 1536);
    transpose_bf16<<<dim3(48, 16), dim3(32, 8), 0, stream>>>(rker, Rt, 512, 1536);
    convert_x<<<512, 256, 0, stream>>>(x, Xb);
    hipMemsetAsync(hf0, 0, 786432, stream);   // hf0 + hbf0 are contiguous

    // Phase 1: MX = Xsel @ kernel + input_bias
    gemm_mx<<<dim3(N3 / 64, 2048 / 64), 256, 0, stream>>>(Xb, Kt, ibias, MX);

    // Phase 2: 8 fused GRU steps
    for (int c = 0; c < 8; ++c) {
        const __hip_bfloat16* hb_in = (c & 1) ? hbf1 : hbf0;
        const float*          hf_in = (c & 1) ? hf1 : hf0;
        float*          hf_o = (c == 7) ? out : ((c & 1) ? hf0 : hf1);
        __hip_bfloat16* hb_o = (c & 1) ? hbf0 : hbf1;
        gru_step<<<dim3(UU / 32, BB / 32), 256, 0, stream>>>(
            hb_in, hf_in, Rt, rbias, MX + (long)c * BB * N3, hf_o, hb_o);
    }
}

// Round 5
// 114.901 us; speedup vs baseline: 2.5188x; 1.0854x over previous
//
#include <hip/hip_runtime.h>
#include <hip/hip_bf16.h>
#include <math.h>

// SkipGRU on MI355X, round 5: remove the 56.7us in-graph memset (45% of the
// graph!) by special-casing step 0 (h0 == 0 -> mi = rbias, pure elementwise).
//
// Only chain j=23 contributes to outputs[:, -1, :]  (t=191 = chunk 7 lane 23,
// lanes independent): 8 sequential GRU steps over x[:, c*24+23, :], h[256,512].
//
// Phase 0: transpose-convert weights to bf16 W^T[N][K]; gather+convert x rows.
// Phase 1: MX[c*256+b][3U] = Xsel @ kernel + input_bias   (bf16 MFMA, fp32 out)
// Phase 2: step 0 elementwise-only; steps 1..7 fused (h @ R + rbias) -> GRU.
//
// mfma_f32_16x16x32_bf16 layouts (learn_hip m89-verified):
//   A: lane l holds A[l&15][(l>>4)*8 + j]  (8 contiguous k -> bf16x8 load)
//   B: lane l holds B[(l>>4)*8 + j][l&15]  (B^T row-major -> contiguous load)
//   D: lane l reg q -> row (l>>4)*4+q, col l&15

typedef float f32x4 __attribute__((ext_vector_type(4)));
typedef short short8 __attribute__((ext_vector_type(8)));

#define BB 256
#define UU 512
#define KK 512
#define N3 1536

__device__ __forceinline__ float sigmoidf_(float s) {
    return 1.0f / (1.0f + __expf(-s));
}

// W[R][C] f32  ->  Wt[C][R] bf16   (LDS-tiled transpose)
__global__ __launch_bounds__(256)
void transpose_bf16(const float* __restrict__ W, __hip_bfloat16* __restrict__ Wt,
                    int R, int C)
{
    __shared__ float tile[32][33];
    const int x = threadIdx.x;          // 0..31
    const int y = threadIdx.y;          // 0..7
    const int c0 = blockIdx.x * 32;
    const int r0 = blockIdx.y * 32;
    #pragma unroll
    for (int i = 0; i < 32; i += 8)
        tile[y + i][x] = W[(long)(r0 + y + i) * C + c0 + x];
    __syncthreads();
    #pragma unroll
    for (int i = 0; i < 32; i += 8)
        Wt[(long)(c0 + y + i) * R + r0 + x] = __float2bfloat16(tile[x][y + i]);
}

// Gather the 8 needed timesteps of x and convert to bf16: Xb[c*256+b][k]
__global__ __launch_bounds__(256)
void convert_x(const float* __restrict__ x, __hip_bfloat16* __restrict__ Xb)
{
    const int idx = blockIdx.x * 256 + threadIdx.x;   // one thread per 8 elems
    const int e = idx * 8;
    const int m = e >> 9;              // 0..2047 = c*256+b
    const int kk = e & 511;
    const int b = m & 255, c = m >> 8;
    const float* src = x + (long)b * (192 * 512) + (long)(c * 24 + 23) * 512 + kk;
    float4 v0 = *(const float4*)src;
    float4 v1 = *(const float4*)(src + 4);
    __hip_bfloat16* dst = Xb + (long)m * 512 + kk;
    dst[0] = __float2bfloat16(v0.x);
    dst[1] = __float2bfloat16(v0.y);
    dst[2] = __float2bfloat16(v0.z);
    dst[3] = __float2bfloat16(v0.w);
    dst[4] = __float2bfloat16(v1.x);
    dst[5] = __float2bfloat16(v1.y);
    dst[6] = __float2bfloat16(v1.z);
    dst[7] = __float2bfloat16(v1.w);
}

// MX = A @ Kt^T + bias:  A[2048][512] bf16, Kt[1536][512] bf16 (=W^T), out f32.
// WG = 4 waves; wave = 16 rows x 64 cols (4 frags). Grid (1536/64, 2048/64).
__global__ __launch_bounds__(256)
void gemm_mx(const __hip_bfloat16* __restrict__ A,
             const __hip_bfloat16* __restrict__ Bt,
             const float* __restrict__ bias,
             float* __restrict__ C)
{
    const int tid = threadIdx.x;
    const int lane = tid & 63;
    const int wid = tid >> 6;                    // 0..3
    const int m0 = blockIdx.y * 64 + wid * 16;
    const int n0 = blockIdx.x * 64;
    const int lr = lane & 15;
    const int lk = (lane >> 4) * 8;

    const short8* ap = (const short8*)(A + (long)(m0 + lr) * KK + lk);
    const short8* bp = (const short8*)(Bt + (long)(n0 + lr) * KK + lk);

    f32x4 acc[4] = {{0.f,0.f,0.f,0.f},{0.f,0.f,0.f,0.f},
                    {0.f,0.f,0.f,0.f},{0.f,0.f,0.f,0.f}};
    #pragma unroll
    for (int k = 0; k < 16; ++k) {               // k0 = 32*k
        short8 a = ap[k * 4];
        #pragma unroll
        for (int t = 0; t < 4; ++t) {
            short8 b = bp[t * 1024 + k * 4];     // +16 rows = 16*512/8 short8
            acc[t] = __builtin_amdgcn_mfma_f32_16x16x32_bf16(a, b, acc[t], 0, 0, 0);
        }
    }
    const int row = (lane >> 4) * 4;
    #pragma unroll
    for (int t = 0; t < 4; ++t) {
        const int u = n0 + t * 16 + lr;
        const float bi = bias[u];
        #pragma unroll
        for (int q = 0; q < 4; ++q)
            C[(long)(m0 + row + q) * N3 + u] = acc[t][q] + bi;
    }
}

// Step 0 (h==0): mi = rbias, so pure elementwise from MX chunk 0.
// h1 = (1-z)*relu(xh + r*rbh), z = sig(xz+rbz), r = sig(xr+rbr).
__global__ __launch_bounds__(256)
void gru_step0(const float* __restrict__ MX0,         // [256][1536] f32
               const float* __restrict__ rbias,       // [1536]
               float* __restrict__ hf_out,            // [256][512] f32
               __hip_bfloat16* __restrict__ hbf_out)  // [256][512] bf16
{
    const int idx = blockIdx.x * 256 + threadIdx.x;   // b*512 + u
    const int b = idx >> 9;
    const int u = idx & 511;
    const float* mx = MX0 + (long)b * N3;
    const float z = sigmoidf_(mx[u]          + rbias[u]);
    const float r = sigmoidf_(mx[u + UU]     + rbias[u + UU]);
    const float cand = mx[u + 2 * UU] + r * rbias[u + 2 * UU];
    const float hh = fmaxf(cand, 0.0f);
    const float hn = (1.0f - z) * hh;
    hf_out[idx] = hn;
    hbf_out[idx] = __float2bfloat16(hn);
}

// One fused GRU step: MI = h @ R + rbias (3 gates), then elementwise update.
// Each wave owns one 16x16 (m,u) tile across ALL 3 gates -> lane-local fusion.
// Grid (512/32, 256/32), WG = 4 waves (2x2 tiles of 16x16).
__global__ __launch_bounds__(256)
void gru_step(const __hip_bfloat16* __restrict__ hbf,  // [256][512] bf16
              const float* __restrict__ hf,            // [256][512] f32
              const __hip_bfloat16* __restrict__ Rt,   // [1536][512] bf16 (R^T)
              const float* __restrict__ rbias,         // [1536]
              const float* __restrict__ MXc,           // [256][1536] f32
              float* __restrict__ hf_out,              // [256][512] f32
              __hip_bfloat16* __restrict__ hbf_out)    // [256][512] bf16
{
    const int tid = threadIdx.x;
    const int lane = tid & 63;
    const int wid = tid >> 6;
    const int wy = wid >> 1, wx = wid & 1;
    const int m0 = blockIdx.y * 32 + wy * 16;
    const int n0 = blockIdx.x * 32 + wx * 16;
    const int lr = lane & 15;
    const int lk = (lane >> 4) * 8;

    const short8* ap = (const short8*)(hbf + (long)(m0 + lr) * KK + lk);
    const short8* bp = (const short8*)(Rt + (long)(n0 + lr) * KK + lk);
    // gate g is +g*512 rows of Rt = g*512*512/8 = g*32768 short8

    f32x4 az = {0.f,0.f,0.f,0.f}, ar = {0.f,0.f,0.f,0.f}, ah = {0.f,0.f,0.f,0.f};
    #pragma unroll
    for (int k = 0; k < 16; ++k) {
        short8 a  = ap[k * 4];
        short8 bz = bp[k * 4];
        short8 br = bp[32768 + k * 4];
        short8 bh = bp[65536 + k * 4];
        az = __builtin_amdgcn_mfma_f32_16x16x32_bf16(a, bz, az, 0, 0, 0);
        ar = __builtin_amdgcn_mfma_f32_16x16x32_bf16(a, br, ar, 0, 0, 0);
        ah = __builtin_amdgcn_mfma_f32_16x16x32_bf16(a, bh, ah, 0, 0, 0);
    }

    const int row = (lane >> 4) * 4;
    const int u = n0 + lr;
    const float rbz = rbias[u];
    const float rbr = rbias[u + UU];
    const float rbh = rbias[u + 2 * UU];
    #pragma unroll
    for (int q = 0; q < 4; ++q) {
        const int m = m0 + row + q;
        const float* mx = MXc + (long)m * N3 + u;
        const float z = sigmoidf_(mx[0]      + az[q] + rbz);
        const float r = sigmoidf_(mx[UU]     + ar[q] + rbr);
        const float rh = ah[q] + rbh;
        const float cand = mx[2 * UU] + r * rh;      // xh + r*rh  (reset_after)
        const float hh = fmaxf(cand, 0.0f);          // relu
        const float hold = hf[(long)m * UU + u];
        const float hn = z * hold + (1.0f - z) * hh;
        hf_out[(long)m * UU + u] = hn;
        hbf_out[(long)m * UU + u] = __float2bfloat16(hn);
    }
}

extern "C" void kernel_launch(void* const* d_in, const int* in_sizes, int n_in,
                              void* d_out, int out_size, void* d_ws, size_t ws_size,
                              hipStream_t stream)
{
    const float* x     = (const float*)d_in[0];   // [256,192,512]
    const float* ker   = (const float*)d_in[1];   // [512,1536]
    const float* rker  = (const float*)d_in[2];   // [512,1536]
    const float* ibias = (const float*)d_in[3];   // [1536]
    const float* rbias = (const float*)d_in[4];   // [1536]
    float* out = (float*)d_out;                   // [256,512]

    char* ws = (char*)d_ws;
    float*          MX   = (float*)ws;                            // 12,582,912 B
    __hip_bfloat16* Xb   = (__hip_bfloat16*)(ws + 12582912);      //  2,097,152 B
    __hip_bfloat16* Kt   = (__hip_bfloat16*)(ws + 14680064);      //  1,572,864 B
    __hip_bfloat16* Rt   = (__hip_bfloat16*)(ws + 16252928);      //  1,572,864 B
    float*          hf0  = (float*)(ws + 17825792);               //    524,288 B
    __hip_bfloat16* hbf0 = (__hip_bfloat16*)(ws + 18350080);      //    262,144 B
    float*          hf1  = (float*)(ws + 18612224);               //    524,288 B
    __hip_bfloat16* hbf1 = (__hip_bfloat16*)(ws + 19136512);      //    262,144 B

    // Phase 0: weight transposes + x gather/convert (no memset needed)
    transpose_bf16<<<dim3(48, 16), dim3(32, 8), 0, stream>>>(ker,  Kt, 512, 1536);
    transpose_bf16<<<dim3(48, 16), dim3(32, 8), 0, stream>>>(rker, Rt, 512, 1536);
    convert_x<<<512, 256, 0, stream>>>(x, Xb);

    // Phase 1: MX = Xsel @ kernel + input_bias
    gemm_mx<<<dim3(N3 / 64, 2048 / 64), 256, 0, stream>>>(Xb, Kt, ibias, MX);

    // Phase 2: step 0 is elementwise-only (h0 == 0); writes hf1/hbf1.
    gru_step0<<<dim3(BB * UU / 256), 256, 0, stream>>>(MX, rbias, hf1, hbf1);

    // Steps 1..7 (same double-buffer parity as before: c odd reads hf1/hbf1)
    for (int c = 1; c < 8; ++c) {
        const __hip_bfloat16* hb_in = (c & 1) ? hbf1 : hbf0;
        const float*          hf_in = (c & 1) ? hf1 : hf0;
        float*          hf_o = (c == 7) ? out : ((c & 1) ? hf0 : hf1);
        __hip_bfloat16* hb_o = (c & 1) ? hbf0 : hbf1;
        gru_step<<<dim3(UU / 32, BB / 32), 256, 0, stream>>>(
            hb_in, hf_in, Rt, rbias, MX + (long)c * BB * N3, hf_o, hb_o);
    }
}